// Round 2
// baseline (179.446 us; speedup 1.0000x reference)
//
#include <hip/hip_runtime.h>

// MonotoneActivation: per (b,g) group of ARITY=4 inputs, sort-4, barycentric
// interpolation over the 2^4 lattice, OUT_DIM=4 outputs.
//
// R10 design = fused mask rebuild (R9) + back to 8 rows/block (2048 blocks =
// 8 blocks/CU = 32 waves/CU, max occupancy) + LOAD-ALL-THEN-COMPUTE split.
//  - R9 post-mortem: 16 rows/block halved the grid -> Occupancy 30%,
//    VALUBusy 18%, hbm 29% => latency-bound. Interleaved load/compute/store
//    also chained load waits behind nt-store completions (shared in-order
//    vmcnt queue).
//  - Fix: issue all 8 X loads first (32 VGPRs of data, explicit window),
//    then compute + nt-store. Load waits no longer sit behind stores.
//  - __launch_bounds__(256,8): cap 64 VGPRs so 8 waves/SIMD fit.
//  - params is binary (0.0/1.0, corner 15 forced 1) -> 64-bit mask/group;
//    selection via (float)bit * coef is exact -> absmax 0.

#define GROUPS        256
#define ROWS_PER_BLK  8
#define BATCH         16384
#define NBLOCKS       (BATCH / ROWS_PER_BLK)   // 2048 = 8 blocks/CU
#define BLOCK_T       256

typedef float f4 __attribute__((ext_vector_type(4)));

__global__ __launch_bounds__(BLOCK_T, 8) void mono_act_fused(
    const float* __restrict__ X,
    const float* __restrict__ params,   // [256][16][4] f32, values in {0,1}
    float* __restrict__ out)            // [BATCH, GROUPS*4]
{
    const int g  = threadIdx.x;                    // group == lane column
    const int r0 = blockIdx.x * ROWS_PER_BLK;

    // ---- rebuild this group's 64-bit lattice bitmask (bit 4e+o = params[g][e][o]) ----
    const f4* __restrict__ P = reinterpret_cast<const f4*>(params) + (g << 4);
    unsigned long long m = 0ull;
    #pragma unroll
    for (int e = 0; e < 16; ++e) {
        const f4 p = P[e];
        const unsigned long long nib =
            (unsigned long long)(p.x != 0.0f)
          | ((unsigned long long)(p.y != 0.0f) << 1)
          | ((unsigned long long)(p.z != 0.0f) << 2)
          | ((unsigned long long)(p.w != 0.0f) << 3);
        m |= nib << (4 * e);
    }

    const f4* __restrict__ X4 = reinterpret_cast<const f4*>(X) + g;
    f4* __restrict__ O4       = reinterpret_cast<f4*>(out) + g;

    // ---- phase 1: issue ALL row loads (8-deep explicit window) ----
    f4 xv[ROWS_PER_BLK];
    #pragma unroll
    for (int k = 0; k < ROWS_PER_BLK; ++k)
        xv[k] = X4[(size_t)(r0 + k) * GROUPS];

    // ---- phase 2: compute + nt-store (stores issued after all loads) ----
    #pragma unroll
    for (int k = 0; k < ROWS_PER_BLK; ++k) {
        const f4 x = xv[k];

        float a0 = x.x, a1 = x.y, a2 = x.z, a3 = x.w;
        int i0 = 1, i1 = 2, i2 = 4, i3 = 8;   // 1 << original index

        // stable sorting network (strict >): (0,1)(2,3)(0,2)(1,3)(1,2)
        // matches jnp.argsort stability; equal values give coef 0 so the
        // tie-broken corner choice cannot change the output anyway.
#define CEX(a, b, ia, ib)                                   \
        do {                                                \
            if (a > b) {                                    \
                float _t = a; a = b; b = _t;                \
                int _u = ia; ia = ib; ib = _u;              \
            }                                               \
        } while (0)
        CEX(a0, a1, i0, i1);
        CEX(a2, a3, i2, i3);
        CEX(a0, a2, i0, i2);
        CEX(a1, a3, i1, i3);
        CEX(a1, a2, i1, i2);
#undef CEX

        const float c0 = a0;
        const float c1 = a1 - a0;
        const float c2 = a2 - a1;
        const float c3 = a3 - a2;

        // reversed-cumsum lattice indices; e0==15 -> corner==1.0 (projected)
        const int e3 = i3;
        const int e2 = e3 | i2;
        const int e1 = e2 | i1;

        // selector nibbles: bit o of s_k = params[g][e_k][o]
        const unsigned int s1 = (unsigned int)(m >> (e1 << 2));
        const unsigned int s2 = (unsigned int)(m >> (e2 << 2));
        const unsigned int s3 = (unsigned int)(m >> (e3 << 2));

        f4 r;
        r.x = c0 + c1 * (float)( s1       & 1)
                 + c2 * (float)( s2       & 1)
                 + c3 * (float)( s3       & 1);
        r.y = c0 + c1 * (float)((s1 >> 1) & 1)
                 + c2 * (float)((s2 >> 1) & 1)
                 + c3 * (float)((s3 >> 1) & 1);
        r.z = c0 + c1 * (float)((s1 >> 2) & 1)
                 + c2 * (float)((s2 >> 2) & 1)
                 + c3 * (float)((s3 >> 2) & 1);
        r.w = c0 + c1 * (float)((s1 >> 3) & 1)
                 + c2 * (float)((s2 >> 3) & 1)
                 + c3 * (float)((s3 >> 3) & 1);

        __builtin_nontemporal_store(r, &O4[(size_t)(r0 + k) * GROUPS]);
    }
}

extern "C" void kernel_launch(void* const* d_in, const int* in_sizes, int n_in,
                              void* d_out, int out_size, void* d_ws, size_t ws_size,
                              hipStream_t stream) {
    const float* X      = (const float*)d_in[0];
    const float* params = (const float*)d_in[1];
    float* out          = (float*)d_out;
    (void)d_ws; (void)ws_size;

    mono_act_fused<<<NBLOCKS, BLOCK_T, 0, stream>>>(X, params, out);
}

// Round 3
// 110.795 us; speedup vs baseline: 1.6196x; 1.6196x over previous
//
#include <hip/hip_runtime.h>

// MonotoneActivation: per (b,g) group of ARITY=4 inputs, sort-4, barycentric
// interpolation over the 2^4 lattice, OUT_DIM=4 outputs.
//
// R11 design = two-kernel (2 KiB mask table in d_ws, proven in R8) +
// 4 rows/block with 4 NAMED load registers + nt stores.
//  - R10 post-mortem: load-all-8 via f4 xv[8] SPILLED (WRITE +80 MiB scratch,
//    FETCH +41 MB, VGPR reported 32). Fix: 4-deep window in named regs.
//  - Two-kernel beats fused at small ROWS_PER_BLK: fused mask rebuild costs
//    16 loads/thread (128 MiB of L2 traffic at 8 rows); the 2 KiB table is
//    one 8-B L2-hot load per thread.
//  - All 4 X loads issue before any compute/store -> no load-wait sits
//    behind an nt-store retirement in the in-order vmcnt queue.
//  - 4096 blocks = 16 blocks/CU queued (8 resident, 2x turnover): store
//    drain of one block overlaps loads of the next.
//  - params is binary (0.0/1.0, corner 15 forced 1) -> 64-bit mask/group;
//    selection via (float)bit * coef is exact -> absmax 0.

#define GROUPS        256
#define ROWS_PER_BLK  4
#define BATCH         16384
#define NBLOCKS       (BATCH / ROWS_PER_BLK)   // 4096
#define BLOCK_T       256

typedef float f4 __attribute__((ext_vector_type(4)));

// ---- kernel 1: compress params [256][16][4] f32 -> 256 x u64 bitmasks ----
__global__ __launch_bounds__(256) void build_masks_kernel(
    const float* __restrict__ params,
    unsigned long long* __restrict__ masks)
{
    const int g = threadIdx.x;                 // one thread per group
    const f4* __restrict__ P = reinterpret_cast<const f4*>(params) + (g << 4);
    unsigned long long m = 0ull;
    #pragma unroll
    for (int e = 0; e < 16; ++e) {
        const f4 p = P[e];
        const unsigned long long nib =
            (unsigned long long)(p.x != 0.0f)
          | ((unsigned long long)(p.y != 0.0f) << 1)
          | ((unsigned long long)(p.z != 0.0f) << 2)
          | ((unsigned long long)(p.w != 0.0f) << 3);
        m |= nib << (4 * e);
    }
    masks[g] = m;
}

// ---- kernel 2: streaming compute, one group-column per thread ----
__global__ __launch_bounds__(BLOCK_T, 8) void mono_act_kernel(
    const float* __restrict__ X,
    const unsigned long long* __restrict__ masks,  // [256], 2 KiB, L2-hot
    float* __restrict__ out)                       // [BATCH, GROUPS*4]
{
    const int g  = threadIdx.x;                    // group == lane column
    const int r0 = blockIdx.x * ROWS_PER_BLK;

    const unsigned long long m = masks[g];

    const f4* __restrict__ X4 = reinterpret_cast<const f4*>(X) + g;
    f4* __restrict__ O4       = reinterpret_cast<f4*>(out) + g;

    const size_t base = (size_t)r0 * GROUPS;       // f4 units

    // ---- issue ALL row loads into NAMED registers (no array -> no scratch) ----
    const f4 x0 = X4[base];
    const f4 x1 = X4[base + GROUPS];
    const f4 x2 = X4[base + 2 * (size_t)GROUPS];
    const f4 x3 = X4[base + 3 * (size_t)GROUPS];

    // sort-4 network + barycentric blend; params bit-selected from mask m.
#define PROCESS(xv, off)                                                  \
    do {                                                                  \
        float a0 = (xv).x, a1 = (xv).y, a2 = (xv).z, a3 = (xv).w;         \
        int i0 = 1, i1 = 2, i2 = 4, i3 = 8;   /* 1 << original index */   \
        /* stable sorting network (strict >): (0,1)(2,3)(0,2)(1,3)(1,2) */\
        if (a0 > a1) { float t=a0;a0=a1;a1=t; int u=i0;i0=i1;i1=u; }      \
        if (a2 > a3) { float t=a2;a2=a3;a3=t; int u=i2;i2=i3;i3=u; }      \
        if (a0 > a2) { float t=a0;a0=a2;a2=t; int u=i0;i0=i2;i2=u; }      \
        if (a1 > a3) { float t=a1;a1=a3;a3=t; int u=i1;i1=i3;i3=u; }      \
        if (a1 > a2) { float t=a1;a1=a2;a2=t; int u=i1;i1=i2;i2=u; }      \
        const float c0 = a0;                                              \
        const float c1 = a1 - a0;                                         \
        const float c2 = a2 - a1;                                         \
        const float c3 = a3 - a2;                                         \
        const int e3 = i3;                                                \
        const int e2 = e3 | i2;                                           \
        const int e1 = e2 | i1;                                           \
        const unsigned int s1 = (unsigned int)(m >> (e1 << 2));           \
        const unsigned int s2 = (unsigned int)(m >> (e2 << 2));           \
        const unsigned int s3 = (unsigned int)(m >> (e3 << 2));           \
        f4 r;                                                             \
        r.x = c0 + c1 * (float)( s1       & 1)                            \
                 + c2 * (float)( s2       & 1)                            \
                 + c3 * (float)( s3       & 1);                           \
        r.y = c0 + c1 * (float)((s1 >> 1) & 1)                            \
                 + c2 * (float)((s2 >> 1) & 1)                            \
                 + c3 * (float)((s3 >> 1) & 1);                           \
        r.z = c0 + c1 * (float)((s1 >> 2) & 1)                            \
                 + c2 * (float)((s2 >> 2) & 1)                            \
                 + c3 * (float)((s3 >> 2) & 1);                           \
        r.w = c0 + c1 * (float)((s1 >> 3) & 1)                            \
                 + c2 * (float)((s2 >> 3) & 1)                            \
                 + c3 * (float)((s3 >> 3) & 1);                           \
        __builtin_nontemporal_store(r, &O4[(off)]);                       \
    } while (0)

    PROCESS(x0, base);
    PROCESS(x1, base + GROUPS);
    PROCESS(x2, base + 2 * (size_t)GROUPS);
    PROCESS(x3, base + 3 * (size_t)GROUPS);
#undef PROCESS
}

extern "C" void kernel_launch(void* const* d_in, const int* in_sizes, int n_in,
                              void* d_out, int out_size, void* d_ws, size_t ws_size,
                              hipStream_t stream) {
    const float* X      = (const float*)d_in[0];
    const float* params = (const float*)d_in[1];
    float* out          = (float*)d_out;
    unsigned long long* masks = (unsigned long long*)d_ws;  // 2 KiB scratch

    build_masks_kernel<<<1, 256, 0, stream>>>(params, masks);
    mono_act_kernel<<<NBLOCKS, BLOCK_T, 0, stream>>>(X, masks, out);
}